// Round 2
// baseline (1436.021 us; speedup 1.0000x reference)
//
#include <hip/hip_runtime.h>

typedef unsigned short u16;
typedef __attribute__((ext_vector_type(8))) short short8;
typedef __attribute__((ext_vector_type(4))) float f32x4;

#define DIMD 512
#define SEQL 2048
#define NTOK 4096   // BATCH*SEQ
#define NHEAD 8
#define HDIM 64
#define NVOCAB 32000
#define BM 128
#define BN 128
#define BK 32

#define MFMA16(a,b,c) __builtin_amdgcn_mfma_f32_16x16x32_bf16(a,b,c,0,0,0)

__device__ __forceinline__ u16 f2b(float f) {
    unsigned int u = __builtin_bit_cast(unsigned int, f);
    u = (u + 0x7FFFu + ((u >> 16) & 1u)) >> 16;
    return (u16)u;
}

__device__ __forceinline__ void async16(const void* g, void* l) {
    __builtin_amdgcn_global_load_lds(
        (const __attribute__((address_space(1))) unsigned int*)g,
        (__attribute__((address_space(3))) unsigned int*)l,
        16, 0, 0);
}

// ---------------- weight f32 -> bf16 conversion ----------------
__global__ void k_cvt(const float4* __restrict__ src, ushort4* __restrict__ dst, int n4) {
    int i = blockIdx.x * 256 + threadIdx.x;
    if (i < n4) {
        float4 f = src[i];
        ushort4 o;
        o.x = f2b(f.x); o.y = f2b(f.y); o.z = f2b(f.z); o.w = f2b(f.w);
        dst[i] = o;
    }
}

// ---------------- embedding + positional encoding (f32 out) ----------------
__global__ void k_embed(const int* __restrict__ seq, const float* __restrict__ emb,
                        float* __restrict__ x) {
    int t = blockIdx.x;          // token 0..4095
    int s = t & (SEQL - 1);      // position
    int tok = seq[t];
    int tid = threadIdx.x;       // 128 threads
    int d = tid * 4;
    float4 e = *(const float4*)&emb[(long)tok * DIMD + d];
    const float kfac = 0.01798894514f; // ln(10000)/512
    float div0 = __expf(-(float)d * kfac);
    float div1 = __expf(-(float)(d + 2) * kfac);
    float a0 = (float)s * div0, a1 = (float)s * div1;
    float4 o;
    o.x = e.x + sinf(a0); o.y = e.y + cosf(a0);
    o.z = e.z + sinf(a1); o.w = e.w + cosf(a1);
    ((float4*)x)[(long)t * 128 + tid] = o;
}

// ---------------- RMSNorm: f32 x -> bf16 out ----------------
__global__ void k_rms(const float* __restrict__ x, const float* __restrict__ w,
                      const float* __restrict__ b, u16* __restrict__ out) {
    int t = blockIdx.x, tid = threadIdx.x;   // 128 threads
    float4 v = ((const float4*)(x + (long)t * DIMD))[tid];
    float ss = v.x * v.x + v.y * v.y + v.z * v.z + v.w * v.w;
#pragma unroll
    for (int m = 1; m < 64; m <<= 1) ss += __shfl_xor(ss, m, 64);
    __shared__ float sred[2];
    if ((tid & 63) == 0) sred[tid >> 6] = ss;
    __syncthreads();
    float inv = rsqrtf((sred[0] + sred[1]) * (1.0f / 512.0f) + 1e-6f);
    float4 wv = ((const float4*)w)[tid];
    float4 bv = ((const float4*)b)[tid];
    ushort4 o;
    o.x = f2b(v.x * inv * wv.x + bv.x);
    o.y = f2b(v.y * inv * wv.y + bv.y);
    o.z = f2b(v.z * inv * wv.z + bv.z);
    o.w = f2b(v.w * inv * wv.w + bv.w);
    ((ushort4*)(out + (long)t * DIMD))[tid] = o;
}

// ---------------- GEMM core: C[M,N] = A[M,K] @ W[N,K]^T, bf16 MFMA ----------------
// MODE 0: store bf16. MODE 1: outF = xio + acc. MODE 2: outF = xio + gelu(acc+bias).
// MODE 3: outF = acc + bias.
template <int MODE>
__device__ __forceinline__ void gemm_core(const u16* __restrict__ A, const u16* __restrict__ W,
                                          const float* __restrict__ bias,
                                          const float* __restrict__ xio,
                                          float* __restrict__ outF, u16* __restrict__ outB,
                                          int N, int K) {
    __shared__ __align__(16) u16 As[BM * BK];
    __shared__ __align__(16) u16 Bs[BN * BK];
    const int tid = threadIdx.x;
    const int w = tid >> 6, lane = tid & 63, quad = lane >> 4, r = lane & 15;
    const int wm0 = (w & 1) << 6, wn0 = (w >> 1) << 6;
    const long arow = (long)blockIdx.x * BM;
    const long wrow = (long)blockIdx.y * BN;

    f32x4 acc[4][4] = {};

    for (int k0 = 0; k0 < K; k0 += BK) {
#pragma unroll
        for (int t = 0; t < 2; ++t) {
            int c = tid + t * 256;
            int row = c >> 2, col = (c & 3) << 3;   // 32-elem rows: 4 chunks/row
            async16(A + (arow + row) * (long)K + k0 + col, (char*)As + c * 16);
            async16(W + (wrow + row) * (long)K + k0 + col, (char*)Bs + c * 16);
        }
        __syncthreads();
        short8 af[4], bf[4];
#pragma unroll
        for (int i = 0; i < 4; i++) af[i] = *(const short8*)&As[(wm0 + i * 16 + r) * BK + quad * 8];
#pragma unroll
        for (int j = 0; j < 4; j++) bf[j] = *(const short8*)&Bs[(wn0 + j * 16 + r) * BK + quad * 8];
#pragma unroll
        for (int i = 0; i < 4; i++)
#pragma unroll
            for (int j = 0; j < 4; j++)
                acc[i][j] = MFMA16(af[i], bf[j], acc[i][j]);
        __syncthreads();
    }

#pragma unroll
    for (int i = 0; i < 4; i++) {
        int rowl = wm0 + i * 16 + quad * 4;
#pragma unroll
        for (int j = 0; j < 4; j++) {
            long gcol = wrow + wn0 + j * 16 + r;
#pragma unroll
            for (int reg = 0; reg < 4; reg++) {
                long grow = arow + rowl + reg;
                long idx = grow * N + gcol;
                float v = acc[i][j][reg];
                if (MODE == 0) {
                    outB[idx] = f2b(v);
                } else if (MODE == 1) {
                    outF[idx] = xio[idx] + v;
                } else if (MODE == 2) {
                    float t0 = v + bias[gcol];
                    float g = 0.5f * t0 * (1.0f + tanhf(0.7978845608028654f * (t0 + 0.044715f * t0 * t0 * t0)));
                    outF[idx] = xio[idx] + g;
                } else {
                    outF[idx] = v + bias[gcol];
                }
            }
        }
    }
}

__global__ __launch_bounds__(256, 2) void k_gemm_qkv(const u16* __restrict__ A,
                                                     const u16* __restrict__ Wq,
                                                     const u16* __restrict__ Wk,
                                                     const u16* __restrict__ Wv,
                                                     u16* __restrict__ oq, u16* __restrict__ ok,
                                                     u16* __restrict__ ov) {
    const u16* W = (blockIdx.z == 0) ? Wq : (blockIdx.z == 1) ? Wk : Wv;
    u16* out = (blockIdx.z == 0) ? oq : (blockIdx.z == 1) ? ok : ov;
    gemm_core<0>(A, W, nullptr, nullptr, nullptr, out, DIMD, DIMD);
}

__global__ __launch_bounds__(256, 2) void k_gemm_resid(const u16* __restrict__ A,
                                                       const u16* __restrict__ W,
                                                       float* __restrict__ x) {
    gemm_core<1>(A, W, nullptr, x, x, nullptr, DIMD, DIMD);
}

__global__ __launch_bounds__(256, 2) void k_gemm_ffn(const u16* __restrict__ A,
                                                     const u16* __restrict__ W,
                                                     const float* __restrict__ bias,
                                                     float* __restrict__ x) {
    gemm_core<2>(A, W, bias, x, x, nullptr, DIMD, DIMD);
}

__global__ __launch_bounds__(256, 2) void k_gemm_head(const u16* __restrict__ A,
                                                      const u16* __restrict__ W,
                                                      const float* __restrict__ bias,
                                                      float* __restrict__ out) {
    gemm_core<3>(A, W, bias, nullptr, out, nullptr, NVOCAB, DIMD);
}

// ---------------- flash attention, block-causal (BLOCK=64) ----------------
// grid: (qblk 0..31, bh 0..15), block 256 (4 waves, 16 q-rows each)
__global__ __launch_bounds__(256, 2) void k_attn(const u16* __restrict__ q,
                                                 const u16* __restrict__ k,
                                                 const u16* __restrict__ v,
                                                 u16* __restrict__ o) {
    __shared__ __align__(16) u16 Ks[64 * 64];       // [kv][d]
    __shared__ __align__(16) u16 VsT[64 * 72];      // [d][kv], stride 72 (16B-aligned rows)
    __shared__ __align__(16) u16 Ps[4][16 * 64];    // per-wave P [q][kv]

    const int qblk = blockIdx.x, bh = blockIdx.y;
    const int b = bh >> 3, h = bh & 7;
    const int tid = threadIdx.x, w = tid >> 6, lane = tid & 63, quad = lane >> 4, r = lane & 15;
    const long base = ((long)b * SEQL) * DIMD + h * HDIM;  // + s*512 + d

    // Q fragments (A-operand): rows w*16 + r of this q-block
    const long qrow = (long)qblk * 64 + w * 16 + r;
    short8 qf0 = *(const short8*)&q[base + qrow * DIMD + quad * 8];
    short8 qf1 = *(const short8*)&q[base + qrow * DIMD + 32 + quad * 8];

    float m_i[4] = {-1e30f, -1e30f, -1e30f, -1e30f};
    float l_i[4] = {0.f, 0.f, 0.f, 0.f};
    f32x4 oacc[4] = {};   // [d-tile], rows via reg

    for (int kb = 0; kb <= qblk; ++kb) {
        const long kv0 = (long)kb * 64;
        // stage K (async) and V (register transpose into VsT)
        // 64-elem rows: 8 chunks of 16B per row, 512 chunks total
#pragma unroll
        for (int t = 0; t < 2; ++t) {
            int c = tid + t * 256;
            int row = c >> 3, col = (c & 7) << 3;
            async16(&k[base + (kv0 + row) * DIMD + col], (char*)Ks + c * 16);
            uint4 pv = *(const uint4*)&v[base + (kv0 + row) * DIMD + col];
            const u16* pe = (const u16*)&pv;
#pragma unroll
            for (int i2 = 0; i2 < 8; i2++) VsT[(col + i2) * 72 + row] = pe[i2];
        }
        __syncthreads();

        // S = Q K^T * scale   (C-layout: row q = quad*4+reg, col kv = jj*16 + r)
        f32x4 s0[4];
#pragma unroll
        for (int jj = 0; jj < 4; jj++) {
            short8 kf0 = *(const short8*)&Ks[(jj * 16 + r) * 64 + quad * 8];
            short8 kf1 = *(const short8*)&Ks[(jj * 16 + r) * 64 + 32 + quad * 8];
            f32x4 z = {};
            z = MFMA16(qf0, kf0, z);
            z = MFMA16(qf1, kf1, z);
            s0[jj] = z * 0.125f;
        }

        // online softmax per q-row (reg selects row; reduce across 16 kv lanes)
#pragma unroll
        for (int reg = 0; reg < 4; ++reg) {
            float mx = fmaxf(fmaxf(s0[0][reg], s0[1][reg]), fmaxf(s0[2][reg], s0[3][reg]));
#pragma unroll
            for (int msk = 1; msk < 16; msk <<= 1) mx = fmaxf(mx, __shfl_xor(mx, msk, 64));
            float mnew = fmaxf(m_i[reg], mx);
            float alpha = __expf(m_i[reg] - mnew);
            m_i[reg] = mnew;
            float p[4], rs = 0.f;
#pragma unroll
            for (int jj = 0; jj < 4; jj++) { p[jj] = __expf(s0[jj][reg] - mnew); rs += p[jj]; }
#pragma unroll
            for (int msk = 1; msk < 16; msk <<= 1) rs += __shfl_xor(rs, msk, 64);
            l_i[reg] = l_i[reg] * alpha + rs;
#pragma unroll
            for (int jd = 0; jd < 4; jd++) oacc[jd][reg] *= alpha;
#pragma unroll
            for (int jj = 0; jj < 4; jj++) Ps[w][(quad * 4 + reg) * 64 + jj * 16 + r] = f2b(p[jj]);
        }

        // O += P V : A-frag from Ps, B-frag from VsT
        short8 pa0 = *(const short8*)&Ps[w][r * 64 + quad * 8];
        short8 pa1 = *(const short8*)&Ps[w][r * 64 + 32 + quad * 8];
#pragma unroll
        for (int jd = 0; jd < 4; jd++) {
            short8 vb0 = *(const short8*)&VsT[(jd * 16 + r) * 72 + quad * 8];
            short8 vb1 = *(const short8*)&VsT[(jd * 16 + r) * 72 + 32 + quad * 8];
            oacc[jd] = MFMA16(pa0, vb0, oacc[jd]);
            oacc[jd] = MFMA16(pa1, vb1, oacc[jd]);
        }
        __syncthreads();
    }

    // epilogue: O / l  (C-layout rows quad*4+reg)
#pragma unroll
    for (int jd = 0; jd < 4; jd++) {
#pragma unroll
        for (int reg = 0; reg < 4; reg++) {
            long qg = (long)qblk * 64 + w * 16 + quad * 4 + reg;
            long dg = h * HDIM + jd * 16 + r;
            o[((long)b * SEQL + qg) * DIMD + dg] = f2b(oacc[jd][reg] / l_i[reg]);
        }
    }
}

// ---------------- host launch ----------------
extern "C" void kernel_launch(void* const* d_in, const int* in_sizes, int n_in,
                              void* d_out, int out_size, void* d_ws, size_t ws_size,
                              hipStream_t stream) {
    const int* seq = (const int*)d_in[0];
    const float* emb = (const float*)d_in[1];
    const float* wq = (const float*)d_in[2];
    const float* wk = (const float*)d_in[3];
    const float* wv = (const float*)d_in[4];
    const float* wo = (const float*)d_in[5];
    const float* ffw = (const float*)d_in[6];
    const float* ffb = (const float*)d_in[7];
    const float* n1w = (const float*)d_in[8];
    const float* n1b = (const float*)d_in[9];
    const float* n2w = (const float*)d_in[10];
    const float* n2b = (const float*)d_in[11];
    const float* fnw = (const float*)d_in[12];
    const float* fnb = (const float*)d_in[13];
    const float* hw = (const float*)d_in[14];
    const float* hb = (const float*)d_in[15];
    float* out = (float*)d_out;

    char* p = (char*)d_ws;
    float* x = (float*)p;      p += (long)NTOK * DIMD * 4;
    u16* hbuf = (u16*)p;       p += (long)NTOK * DIMD * 2;
    u16* qb = (u16*)p;         p += (long)NTOK * DIMD * 2;
    u16* kb = (u16*)p;         p += (long)NTOK * DIMD * 2;
    u16* vb = (u16*)p;         p += (long)NTOK * DIMD * 2;
    u16* ob = (u16*)p;         p += (long)NTOK * DIMD * 2;
    u16* wqb = (u16*)p;        p += (long)4 * DIMD * DIMD * 2;
    u16* wkb = (u16*)p;        p += (long)4 * DIMD * DIMD * 2;
    u16* wvb = (u16*)p;        p += (long)4 * DIMD * DIMD * 2;
    u16* wob = (u16*)p;        p += (long)4 * DIMD * DIMD * 2;
    u16* ffwb = (u16*)p;       p += (long)4 * DIMD * DIMD * 2;
    u16* hwb = (u16*)p;        p += (long)NVOCAB * DIMD * 2;

    // weight conversion
    k_cvt<<<1024, 256, 0, stream>>>((const float4*)wq, (ushort4*)wqb, 262144);
    k_cvt<<<1024, 256, 0, stream>>>((const float4*)wk, (ushort4*)wkb, 262144);
    k_cvt<<<1024, 256, 0, stream>>>((const float4*)wv, (ushort4*)wvb, 262144);
    k_cvt<<<1024, 256, 0, stream>>>((const float4*)wo, (ushort4*)wob, 262144);
    k_cvt<<<1024, 256, 0, stream>>>((const float4*)ffw, (ushort4*)ffwb, 262144);
    k_cvt<<<16000, 256, 0, stream>>>((const float4*)hw, (ushort4*)hwb, 4096000);

    k_embed<<<NTOK, 128, 0, stream>>>(seq, emb, x);

    for (int l = 0; l < 4; ++l) {
        long woff = (long)l * DIMD * DIMD;
        k_rms<<<NTOK, 128, 0, stream>>>(x, n1w + l * DIMD, n1b + l * DIMD, hbuf);
        k_gemm_qkv<<<dim3(32, 4, 3), 256, 0, stream>>>(hbuf, wqb + woff, wkb + woff, wvb + woff,
                                                       qb, kb, vb);
        k_attn<<<dim3(32, 16), 256, 0, stream>>>(qb, kb, vb, ob);
        k_gemm_resid<<<dim3(32, 4), 256, 0, stream>>>(ob, wob + woff, x);
        k_rms<<<NTOK, 128, 0, stream>>>(x, n2w + l * DIMD, n2b + l * DIMD, hbuf);
        k_gemm_ffn<<<dim3(32, 4), 256, 0, stream>>>(hbuf, ffwb + woff, ffb + l * DIMD, x);
    }

    k_rms<<<NTOK, 128, 0, stream>>>(x, fnw, fnb, hbuf);
    k_gemm_head<<<dim3(32, 250), 256, 0, stream>>>(hbuf, hwb, hb, out);
    (void)in_sizes; (void)n_in; (void)out_size; (void)ws_size;
}